// Round 1
// baseline (48.048 us; speedup 1.0000x reference)
//
#include <hip/hip_runtime.h>
#include <math.h>

// Problem constants (from reference)
#define BATCH      1024
#define NB_REQ     8
#define INPUT_DIM  512
#define MAX_DEPTH  17

// One wave (64 lanes) per (batch, req) pair. 8192 pairs total.
// Each lane owns 8 contiguous elements of the 512-d vectors.
__global__ __launch_bounds__(256) void huffmax_kernel(
    const float* __restrict__ x,        // (BATCH, INPUT_DIM)
    const int*   __restrict__ targets,  // (BATCH, NB_REQ)
    const float* __restrict__ W,        // (N_NODES, INPUT_DIM)
    const float* __restrict__ bias,     // (N_NODES,)
    const int*   __restrict__ path,     // (NB_CLASSES, MAX_DEPTH)
    const float* __restrict__ codes,    // (NB_CLASSES, MAX_DEPTH)
    float*       __restrict__ out)      // (BATCH, NB_REQ)
{
    const int wave = threadIdx.x >> 6;
    const int lane = threadIdx.x & 63;
    const int pair = blockIdx.x * 4 + wave;      // 0 .. 8191
    if (pair >= BATCH * NB_REQ) return;
    const int bi = pair >> 3;                    // batch index

    // Load this batch row of x into registers: 8 floats / lane (2x float4).
    const float4* xrow = reinterpret_cast<const float4*>(x + (long)bi * INPUT_DIM);
    const float4 x0 = xrow[lane * 2 + 0];
    const float4 x1 = xrow[lane * 2 + 1];

    const int cls = targets[pair];
    const int*   prow = path  + (long)cls * MAX_DEPTH;
    const float* hrow = codes + (long)cls * MAX_DEPTH;

    float prod = 1.0f;
    for (int d = 0; d < MAX_DEPTH; ++d) {
        const int node = prow[d];                       // wave-uniform
        const float4* wrow =
            reinterpret_cast<const float4*>(W + (long)node * INPUT_DIM);
        const float4 w0 = wrow[lane * 2 + 0];
        const float4 w1 = wrow[lane * 2 + 1];

        float acc = x0.x * w0.x + x0.y * w0.y + x0.z * w0.z + x0.w * w0.w
                  + x1.x * w1.x + x1.y * w1.y + x1.z * w1.z + x1.w * w1.w;

        // 64-lane butterfly reduce; every lane ends with the full dot.
        #pragma unroll
        for (int off = 32; off > 0; off >>= 1)
            acc += __shfl_xor(acc, off, 64);

        const float y = acc + bias[node];
        const float p = 1.0f / (1.0f + expf(-y));
        const float h = hrow[d];
        prod *= (h + p - 2.0f * h * p);   // p if h==0 else 1-p (matches ref exactly)
    }

    if (lane == 0) out[pair] = prod;
}

extern "C" void kernel_launch(void* const* d_in, const int* in_sizes, int n_in,
                              void* d_out, int out_size, void* d_ws, size_t ws_size,
                              hipStream_t stream) {
    const float* x       = (const float*)d_in[0];  // input_vector (1024, 512)
    const int*   targets = (const int*)  d_in[1];  // target_classes (1024, 8)
    const float* W       = (const float*)d_in[2];  // W (99999, 512)
    const float* bias    = (const float*)d_in[3];  // b (99999,)
    const int*   path    = (const int*)  d_in[4];  // class_path_map (100000, 17)
    const float* codes   = (const float*)d_in[5];  // huffman_codes (100000, 17)
    float*       out     = (float*)d_out;          // (1024, 8)

    const int pairs  = BATCH * NB_REQ;             // 8192
    const int blocks = pairs / 4;                  // 4 waves (pairs) per 256-thr block

    huffmax_kernel<<<blocks, 256, 0, stream>>>(x, targets, W, bias, path, codes, out);
}